// Round 7
// baseline (102.903 us; speedup 1.0000x reference)
//
#include <hip/hip_runtime.h>
#include <hip/hip_fp16.h>

// DRR ray-casting for MI355X — round 7.
// r6 failed to get MLP: compiler serialized the interleaved samples (VGPR=32).
// r7: explicit depth-2 software pipeline with loop-carried Smp structs +
// sched_barrier(0) so the 8 next-stage loads stay issued before the current
// consume (~8 loads in flight/lane), and 64x1 lane map (lane = u) so each
// gather spans ~5 cache lines instead of ~8.

static __device__ __constant__ float kPX     = 1.6875f;
static __device__ __constant__ float kPIERCE = 216.0f;
static __device__ __constant__ float kSAD    = 742.5f;
static __device__ __constant__ float kDAD    = 517.15f;

#define VOL_BYTES   (256u * 256u * 256u * 4u)
#define PAIR_R      258u
#define PAIR_ELEMS  (256u * 256u * PAIR_R)          // half2 elements
#define PAIR_BYTES  (PAIR_ELEMS * 4u)

__global__ void drr_init_mm(unsigned* mm) {
    int i = threadIdx.x;
    if (i < 4) mm[i] = (i & 1) ? 0u : 0x7F800000u;  // max<-0, min<-+inf
}

// ---------------- pack: vol[x][y][z] -> vhp[z][y][i] = (v[i-1], v[i]) fp16 ---
__global__ __launch_bounds__(256) void drr_pack(const float* __restrict__ vol,
                                                __half2* __restrict__ vhp,
                                                unsigned* __restrict__ mm) {
    if (blockIdx.x == 0 && threadIdx.x < 4)
        mm[threadIdx.x] = (threadIdx.x & 1) ? 0u : 0x7F800000u;

    __shared__ float tile[65][65];
    const int bid  = blockIdx.x;
    const int y    = bid >> 4;
    const int t4   = bid & 15;
    const int x0   = (t4 & 3) << 6;
    const int z0   = (t4 >> 2) << 6;

    const int rr = threadIdx.x >> 4;   // 0..15 row within pass
    const int cc = threadIdx.x & 15;   // 0..15 float4 column
    #pragma unroll
    for (int base = 0; base < 80; base += 16) {
        const int r = base + rr;
        if (r < 65) {
            const int x = x0 - 1 + r;
            float4 f = make_float4(0.0f, 0.0f, 0.0f, 0.0f);
            if (x >= 0)
                f = *(const float4*)&vol[(x << 16) | (y << 8) | (z0 + (cc << 2))];
            tile[r][(cc << 2) + 0] = f.x;
            tile[r][(cc << 2) + 1] = f.y;
            tile[r][(cc << 2) + 2] = f.z;
            tile[r][(cc << 2) + 3] = f.w;
        }
    }
    __syncthreads();

    const int lane = threadIdx.x & 63;
    const int row4 = threadIdx.x >> 6;  // 0..3
    for (int r = row4; r < 64; r += 4) {
        const int z = z0 + r;
        const unsigned base = (unsigned)((z << 8) | y) * PAIR_R;
        vhp[base + x0 + lane] =
            __halves2half2(__float2half(tile[lane][r]), __float2half(tile[lane + 1][r]));
    }
    if ((t4 & 3) == 3) {
        for (int r = row4; r < 64; r += 4) {
            const int z = z0 + r;
            const unsigned base = (unsigned)((z << 8) | y) * PAIR_R;
            if (lane == 0) {
                vhp[base + 256] = __halves2half2(__float2half(tile[64][r]), __float2half(0.0f));
                vhp[base + 257] = __halves2half2(__float2half(0.0f), __float2half(0.0f));
            }
        }
    }
}

// Per-dimension slab: tighten [tlo, thi] to where s + t*r is in [lo, hi].
__device__ __forceinline__ void slab(float s, float r, float lo, float hi,
                                     float& tlo, float& thi) {
    if (fabsf(r) > 1e-8f) {
        const float inv = 1.0f / r;
        const float ta  = (lo - s) * inv;
        const float tb  = (hi - s) * inv;
        tlo = fmaxf(tlo, fminf(ta, tb));
        thi = fminf(thi, fmaxf(ta, tb));
    } else if (s < lo || s > hi) {
        tlo = 2.0f; thi = -1.0f;  // empty
    }
}

struct RayCfg {
    float sx, sy, sz, rx, ry, rz, length;
    int k_lo, k_hi;
};

__device__ __forceinline__ RayCfg ray_setup(const float* __restrict__ batch,
                                            int b, int u, int v) {
    const float a  = batch[b * 6 + 0];
    const float be = batch[b * 6 + 1];
    const float g  = batch[b * 6 + 2];
    const float tx = batch[b * 6 + 3];
    const float ty = batch[b * 6 + 4];
    const float tz = batch[b * 6 + 5];

    float sa, ca, sb, cb, sg, cg;
    sincosf(a, &sa, &ca);
    sincosf(be, &sb, &cb);
    sincosf(g, &sg, &cg);

    const float R00 = ca * cb;
    const float R01 = ca * sb * sg - sa * cg;
    const float R02 = sa * sg + ca * sb * cg;
    const float R10 = sa * cb;
    const float R11 = ca * cg + sa * sb * sg;
    const float R12 = sa * sb * cg - ca * sg;
    const float R20 = -sb;
    const float R21 = cb * sg;
    const float R22 = cb * cg;

    RayCfg c;
    c.sx = 128.0f + tx + kSAD * R02;
    c.sy = 128.0f + ty + kSAD * R12;
    c.sz = 128.0f + tz + kSAD * R22;

    const float uu = u * kPX - kPIERCE;
    const float vv = v * kPX - kPIERCE;
    c.rx = uu * R00 + vv * R01 - (kSAD + kDAD) * R02;
    c.ry = uu * R10 + vv * R11 - (kSAD + kDAD) * R12;
    c.rz = uu * R20 + vv * R21 - (kSAD + kDAD) * R22;
    c.length = sqrtf(c.rx * c.rx + c.ry * c.ry + c.rz * c.rz);

    float tlo = 0.0f, thi = 1.0f;
    slab(c.sx, c.rx, -1.02f, 256.02f, tlo, thi);
    slab(c.sy, c.ry, -1.02f, 256.02f, tlo, thi);
    slab(c.sz, c.rz, -1.02f, 256.02f, tlo, thi);
    c.k_lo = 0; c.k_hi = -1;
    if (thi >= tlo) {
        c.k_lo = max(0,   (int)ceilf(tlo * 255.0f - 1e-3f));
        c.k_hi = min(255, (int)floorf(thi * 255.0f + 1e-3f));
    }
    return c;
}

// One in-flight trilinear sample: 4 half2 values + 6 weights.
// Out-of-volume samples contribute exactly 0 via the weights (clamped loads
// are always multiplied by zero), so callers may evaluate any k safely.
struct Smp {
    __half2 q00, q01, q10, q11;
    float wx0, wx1, wy0, wy1, wz0, wz1;
};

__device__ __forceinline__ Smp smp_issue(const __half2* __restrict__ vhp,
                                         const RayCfg& c, float t) {
    Smp s;
    const float px = fmaf(t, c.rx, c.sx);
    const float py = fmaf(t, c.ry, c.sy);
    const float pz = fmaf(t, c.rz, c.sz);

    const float fx = floorf(px), fy = floorf(py), fz = floorf(pz);
    const int ix = (int)fx, iy = (int)fy, iz = (int)fz;
    const float wx = px - fx, wy = py - fy, wz = pz - fz;

    const float mx0 = ((unsigned)ix       < 256u) ? 1.0f : 0.0f;
    const float mx1 = ((unsigned)(ix + 1) < 256u) ? 1.0f : 0.0f;
    const float my0 = ((unsigned)iy       < 256u) ? 1.0f : 0.0f;
    const float my1 = ((unsigned)(iy + 1) < 256u) ? 1.0f : 0.0f;
    const float mz0 = ((unsigned)iz       < 256u) ? 1.0f : 0.0f;
    const float mz1 = ((unsigned)(iz + 1) < 256u) ? 1.0f : 0.0f;

    s.wx0 = (1.0f - wx) * mx0; s.wx1 = wx * mx1;
    s.wy0 = (1.0f - wy) * my0; s.wy1 = wy * my1;
    s.wz0 = (1.0f - wz) * mz0; s.wz1 = wz * mz1;

    const int i = min(max(ix + 1, 0), 257);
    const unsigned uy0 = (unsigned)iy & 255u, uy1 = (unsigned)(iy + 1) & 255u;
    const unsigned uz0 = (unsigned)iz & 255u, uz1 = (unsigned)(iz + 1) & 255u;

    // idx = (uz*256 + uy)*258 + i
    const unsigned zt0 = (uz0 << 16) + (uz0 << 9);
    const unsigned zt1 = (uz1 << 16) + (uz1 << 9);
    const unsigned yt0 = (uy0 << 8) + (uy0 << 1);
    const unsigned yt1 = (uy1 << 8) + (uy1 << 1);

    s.q00 = vhp[zt0 + yt0 + i];  // (v000, v100)
    s.q01 = vhp[zt1 + yt0 + i];  // (v001, v101)
    s.q10 = vhp[zt0 + yt1 + i];  // (v010, v110)
    s.q11 = vhp[zt1 + yt1 + i];  // (v011, v111)
    return s;
}

__device__ __forceinline__ float smp_consume(const Smp& s) {
    const float a00 = __low2float(s.q00) * s.wx0 + __high2float(s.q00) * s.wx1;
    const float a01 = __low2float(s.q01) * s.wx0 + __high2float(s.q01) * s.wx1;
    const float a10 = __low2float(s.q10) * s.wx0 + __high2float(s.q10) * s.wx1;
    const float a11 = __low2float(s.q11) * s.wx0 + __high2float(s.q11) * s.wx1;
    return (a00 * s.wz0 + a01 * s.wz1) * s.wy0 + (a10 * s.wz0 + a11 * s.wz1) * s.wy1;
}

// Block = 256 threads = 4 waves; tile = 64x1 pixel strip (lane = u offset).
// Wave `seg` covers k residues {seg, seg+4} mod 8, depth-2 software pipeline:
// issue next stage's 8 loads, sched_barrier, consume current stage.
__global__ __launch_bounds__(256, 4) void drr_main_pk(const __half2* __restrict__ vhp,
                                                      const float* __restrict__ batch,
                                                      float* __restrict__ raw,
                                                      unsigned* __restrict__ mm) {
    const int tid  = threadIdx.x;
    const int lane = tid & 63;
    const int seg  = tid >> 6;

    const int tile = blockIdx.x;
    const int b    = tile >> 10;
    const int ti   = tile & 1023;
    const int u    = ((ti & 3) << 6) + lane;   // 64-pixel u-strip
    const int v    = ti >> 2;                  // one v row

    const RayCfg c = ray_setup(batch, b, u, v);

    const float tstep = 1.0f / 255.0f;
    float sum0 = 0.0f, sum1 = 0.0f;
    int k = c.k_lo + seg;
    if (k <= c.k_hi) {
        Smp A0 = smp_issue(vhp, c, (float)k * tstep);
        Smp A1 = smp_issue(vhp, c, (float)(k + 4) * tstep);
        for (k += 8; k <= c.k_hi; k += 8) {
            Smp B0 = smp_issue(vhp, c, (float)k * tstep);
            Smp B1 = smp_issue(vhp, c, (float)(k + 4) * tstep);
            __builtin_amdgcn_sched_barrier(0);   // keep B loads issued early
            sum0 += smp_consume(A0);
            sum1 += smp_consume(A1);
            A0 = B0; A1 = B1;
        }
        sum0 += smp_consume(A0);
        sum1 += smp_consume(A1);
    }

    __shared__ float part[4][64];
    part[seg][lane] = sum0 + sum1;
    __syncthreads();

    if (tid < 64) {
        const float s = part[0][lane] + part[1][lane] + part[2][lane] + part[3][lane];
        const float rawv = s * (c.length * (1.0f / 256.0f));
        raw[(b << 16) + (v << 8) + u] = rawv;

        float mn = rawv, mx = rawv;
        #pragma unroll
        for (int off = 32; off >= 1; off >>= 1) {
            mn = fminf(mn, __shfl_xor(mn, off));
            mx = fmaxf(mx, __shfl_xor(mx, off));
        }
        if (lane == 0) {
            atomicMin(&mm[2 * b + 0], __float_as_uint(mn));
            atomicMax(&mm[2 * b + 1], __float_as_uint(mx));
        }
    }
}

// ---------------- fallback (ws too small for pair array): f32 path ---------
__global__ __launch_bounds__(256) void drr_transpose(const float* __restrict__ vol,
                                                     float* __restrict__ volt) {
    __shared__ float tile[64][65];
    const int bid  = blockIdx.x;
    const int y    = bid >> 4;
    const int t4   = bid & 15;
    const int x0   = (t4 & 3) << 6;
    const int z0   = (t4 >> 2) << 6;
    const int lane = threadIdx.x & 63;
    const int row4 = threadIdx.x >> 6;

    #pragma unroll
    for (int i = 0; i < 16; ++i) {
        const int xr = (i << 2) + row4;
        tile[xr][lane] = vol[((x0 + xr) << 16) | (y << 8) | (z0 + lane)];
    }
    __syncthreads();
    #pragma unroll
    for (int i = 0; i < 16; ++i) {
        const int zr = (i << 2) + row4;
        volt[((z0 + zr) << 16) | (y << 8) | (x0 + lane)] = tile[lane][zr];
    }
}

__device__ __forceinline__ float tri_sample_f32(const float* __restrict__ vol,
                                                const RayCfg& c, float t) {
    const float px = fmaf(t, c.rx, c.sx);
    const float py = fmaf(t, c.ry, c.sy);
    const float pz = fmaf(t, c.rz, c.sz);
    const float fx = floorf(px), fy = floorf(py), fz = floorf(pz);
    const int ix = (int)fx, iy = (int)fy, iz = (int)fz;
    const float wx = px - fx, wy = py - fy, wz = pz - fz;
    const float mx0 = ((unsigned)ix       < 256u) ? 1.0f : 0.0f;
    const float mx1 = ((unsigned)(ix + 1) < 256u) ? 1.0f : 0.0f;
    const float my0 = ((unsigned)iy       < 256u) ? 1.0f : 0.0f;
    const float my1 = ((unsigned)(iy + 1) < 256u) ? 1.0f : 0.0f;
    const float mz0 = ((unsigned)iz       < 256u) ? 1.0f : 0.0f;
    const float mz1 = ((unsigned)(iz + 1) < 256u) ? 1.0f : 0.0f;
    const unsigned X0 = (unsigned)ix & 255u, X1 = (unsigned)(ix + 1) & 255u;
    const unsigned Y0 = ((unsigned)iy & 255u) << 8, Y1 = ((unsigned)(iy + 1) & 255u) << 8;
    const unsigned Z0 = ((unsigned)iz & 255u) << 16, Z1 = ((unsigned)(iz + 1) & 255u) << 16;
    const float v000 = vol[Z0 | Y0 | X0];
    const float v001 = vol[Z1 | Y0 | X0];
    const float v010 = vol[Z0 | Y1 | X0];
    const float v011 = vol[Z1 | Y1 | X0];
    const float v100 = vol[Z0 | Y0 | X1];
    const float v101 = vol[Z1 | Y0 | X1];
    const float v110 = vol[Z0 | Y1 | X1];
    const float v111 = vol[Z1 | Y1 | X1];
    const float wx0 = (1.0f - wx) * mx0, wx1 = wx * mx1;
    const float wy0 = (1.0f - wy) * my0, wy1 = wy * my1;
    const float wz0 = (1.0f - wz) * mz0, wz1 = wz * mz1;
    const float c00 = v000 * wz0 + v001 * wz1;
    const float c01 = v010 * wz0 + v011 * wz1;
    const float c10 = v100 * wz0 + v101 * wz1;
    const float c11 = v110 * wz0 + v111 * wz1;
    return (c00 * wy0 + c01 * wy1) * wx0 + (c10 * wy0 + c11 * wy1) * wx1;
}

__global__ __launch_bounds__(256, 4) void drr_main_f32(const float* __restrict__ volt,
                                                       const float* __restrict__ batch,
                                                       float* __restrict__ raw,
                                                       unsigned* __restrict__ mm) {
    const int tid  = threadIdx.x;
    const int lane = tid & 63;
    const int seg  = tid >> 6;
    const int tile = blockIdx.x;
    const int b    = tile >> 10;
    const int ti   = tile & 1023;
    const int u    = ((ti & 3) << 6) + lane;
    const int v    = ti >> 2;

    const RayCfg c = ray_setup(batch, b, u, v);

    const float tstep = 1.0f / 255.0f;
    float sum = 0.0f;
    for (int k = c.k_lo + seg; k <= c.k_hi; k += 4)
        sum += tri_sample_f32(volt, c, (float)k * tstep);

    __shared__ float part[4][64];
    part[seg][lane] = sum;
    __syncthreads();

    if (tid < 64) {
        const float s = part[0][lane] + part[1][lane] + part[2][lane] + part[3][lane];
        const float rawv = s * (c.length * (1.0f / 256.0f));
        raw[(b << 16) + (v << 8) + u] = rawv;
        float mn = rawv, mx = rawv;
        #pragma unroll
        for (int off = 32; off >= 1; off >>= 1) {
            mn = fminf(mn, __shfl_xor(mn, off));
            mx = fmaxf(mx, __shfl_xor(mx, off));
        }
        if (lane == 0) {
            atomicMin(&mm[2 * b + 0], __float_as_uint(mn));
            atomicMax(&mm[2 * b + 1], __float_as_uint(mx));
        }
    }
}

__global__ __launch_bounds__(256) void drr_norm(float* __restrict__ img,
                                                const unsigned* __restrict__ mm) {
    const int gid = blockIdx.x * 256 + threadIdx.x;
    const int b   = gid >> 16;
    const float mn  = __uint_as_float(mm[2 * b + 0]);
    const float mx  = __uint_as_float(mm[2 * b + 1]);
    const float inv = 1.0f / (mx - mn);
    img[gid] = 1.0f - (img[gid] - mn) * inv;
}

extern "C" void kernel_launch(void* const* d_in, const int* in_sizes, int n_in,
                              void* d_out, int out_size, void* d_ws, size_t ws_size,
                              hipStream_t stream) {
    const float* vol   = (const float*)d_in[0];
    const float* batch = (const float*)d_in[1];
    float* out         = (float*)d_out;

    if (ws_size >= (size_t)PAIR_BYTES + 16) {
        __half2*  vhp = (__half2*)d_ws;
        unsigned* mm  = (unsigned*)((char*)d_ws + PAIR_BYTES);
        drr_pack<<<4096, 256, 0, stream>>>(vol, vhp, mm);
        drr_main_pk<<<2048, 256, 0, stream>>>(vhp, batch, out, mm);
        drr_norm<<<512, 256, 0, stream>>>(out, mm);
    } else {
        float*    volt = (float*)d_ws;
        unsigned* mm   = (unsigned*)((char*)d_ws + VOL_BYTES);
        drr_init_mm<<<1, 64, 0, stream>>>(mm);
        drr_transpose<<<4096, 256, 0, stream>>>(vol, volt);
        drr_main_f32<<<2048, 256, 0, stream>>>(volt, batch, out, mm);
        drr_norm<<<512, 256, 0, stream>>>(out, mm);
    }
}

// Round 9
// 100.015 us; speedup vs baseline: 1.0289x; 1.0289x over previous
//
#include <hip/hip_runtime.h>
#include <hip/hip_fp16.h>

// DRR ray-casting for MI355X — round 9.
// r8 (asm loads + counted vmcnt) was unsound -> NaN. r9 gets MLP safely:
// plain C loads for 4 samples (16 dwords) + empty keep-alive pin
// asm volatile("" : "+v"(...)) between loads and uses -> compiler must issue
// all 16 loads then wait once (batch-issue-then-wait), ~4x latency amortization
// vs r5/r6's per-sample wait. Overshoot samples use clamped y/z addresses
// (L1-hot) with exactly-zero weights. XCD-aware tile swizzle for L2 bands.

static __device__ __constant__ float kPX     = 1.6875f;
static __device__ __constant__ float kPIERCE = 216.0f;
static __device__ __constant__ float kSAD    = 742.5f;
static __device__ __constant__ float kDAD    = 517.15f;

#define VOL_BYTES   (256u * 256u * 256u * 4u)
#define PAIR_R      258u
#define PAIR_ELEMS  (256u * 256u * PAIR_R)          // half2 elements
#define PAIR_BYTES  (PAIR_ELEMS * 4u)

__global__ void drr_init_mm(unsigned* mm) {
    int i = threadIdx.x;
    if (i < 4) mm[i] = (i & 1) ? 0u : 0x7F800000u;  // max<-0, min<-+inf
}

// ---------------- pack: vol[x][y][z] -> vhp[z][y][i] = (v[i-1], v[i]) fp16 ---
// (unchanged from r6 — proven correct three times)
__global__ __launch_bounds__(256) void drr_pack(const float* __restrict__ vol,
                                                __half2* __restrict__ vhp,
                                                unsigned* __restrict__ mm) {
    if (blockIdx.x == 0 && threadIdx.x < 4)
        mm[threadIdx.x] = (threadIdx.x & 1) ? 0u : 0x7F800000u;

    __shared__ float tile[65][65];
    const int bid  = blockIdx.x;
    const int y    = bid >> 4;
    const int t4   = bid & 15;
    const int x0   = (t4 & 3) << 6;
    const int z0   = (t4 >> 2) << 6;

    const int rr = threadIdx.x >> 4;   // 0..15 row within pass
    const int cc = threadIdx.x & 15;   // 0..15 float4 column
    #pragma unroll
    for (int base = 0; base < 80; base += 16) {
        const int r = base + rr;
        if (r < 65) {
            const int x = x0 - 1 + r;
            float4 f = make_float4(0.0f, 0.0f, 0.0f, 0.0f);
            if (x >= 0)
                f = *(const float4*)&vol[(x << 16) | (y << 8) | (z0 + (cc << 2))];
            tile[r][(cc << 2) + 0] = f.x;
            tile[r][(cc << 2) + 1] = f.y;
            tile[r][(cc << 2) + 2] = f.z;
            tile[r][(cc << 2) + 3] = f.w;
        }
    }
    __syncthreads();

    const int lane = threadIdx.x & 63;
    const int row4 = threadIdx.x >> 6;  // 0..3
    for (int r = row4; r < 64; r += 4) {
        const int z = z0 + r;
        const unsigned base = (unsigned)((z << 8) | y) * PAIR_R;
        vhp[base + x0 + lane] =
            __halves2half2(__float2half(tile[lane][r]), __float2half(tile[lane + 1][r]));
    }
    if ((t4 & 3) == 3) {
        for (int r = row4; r < 64; r += 4) {
            const int z = z0 + r;
            const unsigned base = (unsigned)((z << 8) | y) * PAIR_R;
            if (lane == 0) {
                vhp[base + 256] = __halves2half2(__float2half(tile[64][r]), __float2half(0.0f));
                vhp[base + 257] = __halves2half2(__float2half(0.0f), __float2half(0.0f));
            }
        }
    }
}

// Per-dimension slab: tighten [tlo, thi] to where s + t*r is in [lo, hi].
__device__ __forceinline__ void slab(float s, float r, float lo, float hi,
                                     float& tlo, float& thi) {
    if (fabsf(r) > 1e-8f) {
        const float inv = 1.0f / r;
        const float ta  = (lo - s) * inv;
        const float tb  = (hi - s) * inv;
        tlo = fmaxf(tlo, fminf(ta, tb));
        thi = fminf(thi, fmaxf(ta, tb));
    } else if (s < lo || s > hi) {
        tlo = 2.0f; thi = -1.0f;  // empty
    }
}

struct RayCfg {
    float sx, sy, sz, rx, ry, rz, length;
    int k_lo, k_hi;
};

__device__ __forceinline__ RayCfg ray_setup(const float* __restrict__ batch,
                                            int b, int u, int v) {
    const float a  = batch[b * 6 + 0];
    const float be = batch[b * 6 + 1];
    const float g  = batch[b * 6 + 2];
    const float tx = batch[b * 6 + 3];
    const float ty = batch[b * 6 + 4];
    const float tz = batch[b * 6 + 5];

    float sa, ca, sb, cb, sg, cg;
    sincosf(a, &sa, &ca);
    sincosf(be, &sb, &cb);
    sincosf(g, &sg, &cg);

    const float R00 = ca * cb;
    const float R01 = ca * sb * sg - sa * cg;
    const float R02 = sa * sg + ca * sb * cg;
    const float R10 = sa * cb;
    const float R11 = ca * cg + sa * sb * sg;
    const float R12 = sa * sb * cg - ca * sg;
    const float R20 = -sb;
    const float R21 = cb * sg;
    const float R22 = cb * cg;

    RayCfg c;
    c.sx = 128.0f + tx + kSAD * R02;
    c.sy = 128.0f + ty + kSAD * R12;
    c.sz = 128.0f + tz + kSAD * R22;

    const float uu = u * kPX - kPIERCE;
    const float vv = v * kPX - kPIERCE;
    c.rx = uu * R00 + vv * R01 - (kSAD + kDAD) * R02;
    c.ry = uu * R10 + vv * R11 - (kSAD + kDAD) * R12;
    c.rz = uu * R20 + vv * R21 - (kSAD + kDAD) * R22;
    c.length = sqrtf(c.rx * c.rx + c.ry * c.ry + c.rz * c.rz);

    float tlo = 0.0f, thi = 1.0f;
    slab(c.sx, c.rx, -1.02f, 256.02f, tlo, thi);
    slab(c.sy, c.ry, -1.02f, 256.02f, tlo, thi);
    slab(c.sz, c.rz, -1.02f, 256.02f, tlo, thi);
    c.k_lo = 0; c.k_hi = -1;
    if (thi >= tlo) {
        c.k_lo = max(0,   (int)ceilf(tlo * 255.0f - 1e-3f));
        c.k_hi = min(255, (int)floorf(thi * 255.0f + 1e-3f));
    }
    return c;
}

// One sample's state: 4 loaded dwords (half2 pairs) + 6 weights.
struct Quad {
    unsigned q00, q01, q10, q11;
    float wx0, wx1, wy0, wy1, wz0, wz1;
};

// Compute weights and LOAD the 4 half2 pairs (plain C loads; scheduling is
// forced by the caller's keep-alive pin). Out-of-volume samples get weight 0
// on the OOB side; addresses are CLAMPED (not wrapped) so overshoot samples
// hit already-resident lines.
__device__ __forceinline__ Quad sample_issue(const __half2* __restrict__ vhp,
                                             const RayCfg& c, float t) {
    Quad s;
    const float px = fmaf(t, c.rx, c.sx);
    const float py = fmaf(t, c.ry, c.sy);
    const float pz = fmaf(t, c.rz, c.sz);

    const float fx = floorf(px), fy = floorf(py), fz = floorf(pz);
    const int ix = (int)fx, iy = (int)fy, iz = (int)fz;
    const float wx = px - fx, wy = py - fy, wz = pz - fz;

    const float mx0 = ((unsigned)ix       < 256u) ? 1.0f : 0.0f;
    const float mx1 = ((unsigned)(ix + 1) < 256u) ? 1.0f : 0.0f;
    const float my0 = ((unsigned)iy       < 256u) ? 1.0f : 0.0f;
    const float my1 = ((unsigned)(iy + 1) < 256u) ? 1.0f : 0.0f;
    const float mz0 = ((unsigned)iz       < 256u) ? 1.0f : 0.0f;
    const float mz1 = ((unsigned)(iz + 1) < 256u) ? 1.0f : 0.0f;

    s.wx0 = (1.0f - wx) * mx0; s.wx1 = wx * mx1;
    s.wy0 = (1.0f - wy) * my0; s.wy1 = wy * my1;
    s.wz0 = (1.0f - wz) * mz0; s.wz1 = wz * mz1;

    const int i  = min(max(ix + 1, 0), 257);
    const int y0 = min(max(iy,     0), 255);
    const int y1 = min(max(iy + 1, 0), 255);
    const int z0 = min(max(iz,     0), 255);
    const int z1 = min(max(iz + 1, 0), 255);

    const unsigned zt0 = (unsigned)z0 * 66048u;   // 256*258
    const unsigned zt1 = (unsigned)z1 * 66048u;
    const unsigned yt0 = (unsigned)y0 * 258u;
    const unsigned yt1 = (unsigned)y1 * 258u;

    s.q00 = *(const unsigned*)(vhp + (zt0 + yt0 + i));  // (v000, v100)
    s.q01 = *(const unsigned*)(vhp + (zt1 + yt0 + i));  // (v001, v101)
    s.q10 = *(const unsigned*)(vhp + (zt0 + yt1 + i));  // (v010, v110)
    s.q11 = *(const unsigned*)(vhp + (zt1 + yt1 + i));  // (v011, v111)
    return s;
}

__device__ __forceinline__ float sample_consume(const Quad& s) {
    const __half2 q00 = __builtin_bit_cast(__half2, s.q00);
    const __half2 q01 = __builtin_bit_cast(__half2, s.q01);
    const __half2 q10 = __builtin_bit_cast(__half2, s.q10);
    const __half2 q11 = __builtin_bit_cast(__half2, s.q11);
    const float a00 = __low2float(q00) * s.wx0 + __high2float(q00) * s.wx1;
    const float a01 = __low2float(q01) * s.wx0 + __high2float(q01) * s.wx1;
    const float a10 = __low2float(q10) * s.wx0 + __high2float(q10) * s.wx1;
    const float a11 = __low2float(q11) * s.wx0 + __high2float(q11) * s.wx1;
    return (a00 * s.wz0 + a01 * s.wz1) * s.wy0 + (a10 * s.wz0 + a11 * s.wz1) * s.wy1;
}

// Block = 256 threads = 4 waves; one 16x4 pixel tile. Wave `seg` handles
// contiguous 4-sample chunks starting at k_lo + 4*seg, stride 16. Per
// iteration: 16 loads issued, ONE pin (keep-alive) forces batch-issue-then-
// wait-once, then 4 consumes. Overshoot chunks contribute exactly 0.
__global__ __launch_bounds__(256, 4) void drr_main_pk(const __half2* __restrict__ vhp,
                                                      const float* __restrict__ batch,
                                                      float* __restrict__ raw,
                                                      unsigned* __restrict__ mm) {
    const int tid  = threadIdx.x;
    const int lane = tid & 63;
    const int seg  = tid >> 6;

    // XCD-aware swizzle: each XCD (blockIdx % 8) gets a contiguous 256-tile
    // band -> its private L2 serves one image band. Bijective for 2048 blocks.
    const int tile = ((blockIdx.x & 7) << 8) | (blockIdx.x >> 3);
    const int b    = tile >> 10;
    const int ti   = tile & 1023;
    const int u    = ((ti & 15) << 4) + (lane & 15);   // 16 u-pixels
    const int v    = ((ti >> 4) << 2) + (lane >> 4);   // 4 v-rows

    const RayCfg c = ray_setup(batch, b, u, v);

    const float tstep = 1.0f / 255.0f;
    float sum = 0.0f;
    for (int kb = c.k_lo + (seg << 2); kb <= c.k_hi; kb += 16) {
        Quad s0 = sample_issue(vhp, c, (float)(kb + 0) * tstep);
        Quad s1 = sample_issue(vhp, c, (float)(kb + 1) * tstep);
        Quad s2 = sample_issue(vhp, c, (float)(kb + 2) * tstep);
        Quad s3 = sample_issue(vhp, c, (float)(kb + 3) * tstep);
        // Keep-alive pin: demands all 16 loaded dwords live HERE -> compiler
        // must issue all 16 loads above, wait once, then consume below.
        asm volatile("" :
            "+v"(s0.q00), "+v"(s0.q01), "+v"(s0.q10), "+v"(s0.q11),
            "+v"(s1.q00), "+v"(s1.q01), "+v"(s1.q10), "+v"(s1.q11),
            "+v"(s2.q00), "+v"(s2.q01), "+v"(s2.q10), "+v"(s2.q11),
            "+v"(s3.q00), "+v"(s3.q01), "+v"(s3.q10), "+v"(s3.q11));
        sum += sample_consume(s0) + sample_consume(s1)
             + sample_consume(s2) + sample_consume(s3);
    }

    __shared__ float part[4][64];
    part[seg][lane] = sum;
    __syncthreads();

    if (tid < 64) {
        const float s = part[0][lane] + part[1][lane] + part[2][lane] + part[3][lane];
        const float rawv = s * (c.length * (1.0f / 256.0f));
        raw[(b << 16) + (v << 8) + u] = rawv;

        float mn = rawv, mx = rawv;
        #pragma unroll
        for (int off = 32; off >= 1; off >>= 1) {
            mn = fminf(mn, __shfl_xor(mn, off));
            mx = fmaxf(mx, __shfl_xor(mx, off));
        }
        if (lane == 0) {
            atomicMin(&mm[2 * b + 0], __float_as_uint(mn));
            atomicMax(&mm[2 * b + 1], __float_as_uint(mx));
        }
    }
}

// ---------------- fallback (ws too small for pair array): f32 path ---------
__global__ __launch_bounds__(256) void drr_transpose(const float* __restrict__ vol,
                                                     float* __restrict__ volt) {
    __shared__ float tile[64][65];
    const int bid  = blockIdx.x;
    const int y    = bid >> 4;
    const int t4   = bid & 15;
    const int x0   = (t4 & 3) << 6;
    const int z0   = (t4 >> 2) << 6;
    const int lane = threadIdx.x & 63;
    const int row4 = threadIdx.x >> 6;

    #pragma unroll
    for (int i = 0; i < 16; ++i) {
        const int xr = (i << 2) + row4;
        tile[xr][lane] = vol[((x0 + xr) << 16) | (y << 8) | (z0 + lane)];
    }
    __syncthreads();
    #pragma unroll
    for (int i = 0; i < 16; ++i) {
        const int zr = (i << 2) + row4;
        volt[((z0 + zr) << 16) | (y << 8) | (x0 + lane)] = tile[lane][zr];
    }
}

__device__ __forceinline__ float tri_sample_f32(const float* __restrict__ vol,
                                                const RayCfg& c, float t) {
    const float px = fmaf(t, c.rx, c.sx);
    const float py = fmaf(t, c.ry, c.sy);
    const float pz = fmaf(t, c.rz, c.sz);
    const float fx = floorf(px), fy = floorf(py), fz = floorf(pz);
    const int ix = (int)fx, iy = (int)fy, iz = (int)fz;
    const float wx = px - fx, wy = py - fy, wz = pz - fz;
    const float mx0 = ((unsigned)ix       < 256u) ? 1.0f : 0.0f;
    const float mx1 = ((unsigned)(ix + 1) < 256u) ? 1.0f : 0.0f;
    const float my0 = ((unsigned)iy       < 256u) ? 1.0f : 0.0f;
    const float my1 = ((unsigned)(iy + 1) < 256u) ? 1.0f : 0.0f;
    const float mz0 = ((unsigned)iz       < 256u) ? 1.0f : 0.0f;
    const float mz1 = ((unsigned)(iz + 1) < 256u) ? 1.0f : 0.0f;
    const unsigned X0 = (unsigned)ix & 255u, X1 = (unsigned)(ix + 1) & 255u;
    const unsigned Y0 = ((unsigned)iy & 255u) << 8, Y1 = ((unsigned)(iy + 1) & 255u) << 8;
    const unsigned Z0 = ((unsigned)iz & 255u) << 16, Z1 = ((unsigned)(iz + 1) & 255u) << 16;
    const float v000 = vol[Z0 | Y0 | X0];
    const float v001 = vol[Z1 | Y0 | X0];
    const float v010 = vol[Z0 | Y1 | X0];
    const float v011 = vol[Z1 | Y1 | X0];
    const float v100 = vol[Z0 | Y0 | X1];
    const float v101 = vol[Z1 | Y0 | X1];
    const float v110 = vol[Z0 | Y1 | X1];
    const float v111 = vol[Z1 | Y1 | X1];
    const float wx0 = (1.0f - wx) * mx0, wx1 = wx * mx1;
    const float wy0 = (1.0f - wy) * my0, wy1 = wy * my1;
    const float wz0 = (1.0f - wz) * mz0, wz1 = wz * mz1;
    const float c00 = v000 * wz0 + v001 * wz1;
    const float c01 = v010 * wz0 + v011 * wz1;
    const float c10 = v100 * wz0 + v101 * wz1;
    const float c11 = v110 * wz0 + v111 * wz1;
    return (c00 * wy0 + c01 * wy1) * wx0 + (c10 * wy0 + c11 * wy1) * wx1;
}

__global__ __launch_bounds__(256, 4) void drr_main_f32(const float* __restrict__ volt,
                                                       const float* __restrict__ batch,
                                                       float* __restrict__ raw,
                                                       unsigned* __restrict__ mm) {
    const int tid  = threadIdx.x;
    const int lane = tid & 63;
    const int seg  = tid >> 6;
    const int tile = blockIdx.x;
    const int b    = tile >> 10;
    const int ti   = tile & 1023;
    const int u    = ((ti & 15) << 4) + (lane & 15);
    const int v    = ((ti >> 4) << 2) + (lane >> 4);

    const RayCfg c = ray_setup(batch, b, u, v);

    const float tstep = 1.0f / 255.0f;
    float sum = 0.0f;
    for (int k = c.k_lo + seg; k <= c.k_hi; k += 4)
        sum += tri_sample_f32(volt, c, (float)k * tstep);

    __shared__ float part[4][64];
    part[seg][lane] = sum;
    __syncthreads();

    if (tid < 64) {
        const float s = part[0][lane] + part[1][lane] + part[2][lane] + part[3][lane];
        const float rawv = s * (c.length * (1.0f / 256.0f));
        raw[(b << 16) + (v << 8) + u] = rawv;
        float mn = rawv, mx = rawv;
        #pragma unroll
        for (int off = 32; off >= 1; off >>= 1) {
            mn = fminf(mn, __shfl_xor(mn, off));
            mx = fmaxf(mx, __shfl_xor(mx, off));
        }
        if (lane == 0) {
            atomicMin(&mm[2 * b + 0], __float_as_uint(mn));
            atomicMax(&mm[2 * b + 1], __float_as_uint(mx));
        }
    }
}

__global__ __launch_bounds__(256) void drr_norm(float* __restrict__ img,
                                                const unsigned* __restrict__ mm) {
    const int gid = blockIdx.x * 256 + threadIdx.x;
    const int b   = gid >> 16;
    const float mn  = __uint_as_float(mm[2 * b + 0]);
    const float mx  = __uint_as_float(mm[2 * b + 1]);
    const float inv = 1.0f / (mx - mn);
    img[gid] = 1.0f - (img[gid] - mn) * inv;
}

extern "C" void kernel_launch(void* const* d_in, const int* in_sizes, int n_in,
                              void* d_out, int out_size, void* d_ws, size_t ws_size,
                              hipStream_t stream) {
    const float* vol   = (const float*)d_in[0];
    const float* batch = (const float*)d_in[1];
    float* out         = (float*)d_out;

    if (ws_size >= (size_t)PAIR_BYTES + 16) {
        __half2*  vhp = (__half2*)d_ws;
        unsigned* mm  = (unsigned*)((char*)d_ws + PAIR_BYTES);
        drr_pack<<<4096, 256, 0, stream>>>(vol, vhp, mm);
        drr_main_pk<<<2048, 256, 0, stream>>>(vhp, batch, out, mm);
        drr_norm<<<512, 256, 0, stream>>>(out, mm);
    } else {
        float*    volt = (float*)d_ws;
        unsigned* mm   = (unsigned*)((char*)d_ws + VOL_BYTES);
        drr_init_mm<<<1, 64, 0, stream>>>(mm);
        drr_transpose<<<4096, 256, 0, stream>>>(vol, volt);
        drr_main_f32<<<2048, 256, 0, stream>>>(volt, batch, out, mm);
        drr_norm<<<512, 256, 0, stream>>>(out, mm);
    }
}

// Round 10
// 95.130 us; speedup vs baseline: 1.0817x; 1.0513x over previous
//
#include <hip/hip_runtime.h>
#include <hip/hip_fp16.h>

// DRR ray-casting for MI355X — round 10.
// Cost model locked from r4/r5/r9: T/step = VALU + ~6.3 cyc per distinct 64B
// line touched by the wave's gathers (L1 line-service bound). MLP (r9) and
// instruction count (r5) are secondary. r10 reduces lines/sample:
//  (a) 2 v-adjacent pixels per lane (16x8 tile): row set (y,z combos) is set
//      by pose slopes, ~independent of pixels/lane -> ~0.63 lines/sample vs 0.70.
//  (b) interior fast path: strict in-volume window -> no masks/clamps (bit-exact),
//      ~18 fewer VALU on ~85% of samples.
// 512-thread blocks (8-way k-split) keep 32 waves/CU.

static __device__ __constant__ float kPX     = 1.6875f;
static __device__ __constant__ float kPIERCE = 216.0f;
static __device__ __constant__ float kSAD    = 742.5f;
static __device__ __constant__ float kDAD    = 517.15f;

#define VOL_BYTES   (256u * 256u * 256u * 4u)
#define PAIR_R      258u
#define PAIR_ELEMS  (256u * 256u * PAIR_R)          // half2 elements
#define PAIR_BYTES  (PAIR_ELEMS * 4u)

__global__ void drr_init_mm(unsigned* mm) {
    int i = threadIdx.x;
    if (i < 4) mm[i] = (i & 1) ? 0u : 0x7F800000u;  // max<-0, min<-+inf
}

// ---------------- pack: vol[x][y][z] -> vhp[z][y][i] = (v[i-1], v[i]) fp16 ---
// (unchanged — proven correct four times)
__global__ __launch_bounds__(256) void drr_pack(const float* __restrict__ vol,
                                                __half2* __restrict__ vhp,
                                                unsigned* __restrict__ mm) {
    if (blockIdx.x == 0 && threadIdx.x < 4)
        mm[threadIdx.x] = (threadIdx.x & 1) ? 0u : 0x7F800000u;

    __shared__ float tile[65][65];
    const int bid  = blockIdx.x;
    const int y    = bid >> 4;
    const int t4   = bid & 15;
    const int x0   = (t4 & 3) << 6;
    const int z0   = (t4 >> 2) << 6;

    const int rr = threadIdx.x >> 4;   // 0..15 row within pass
    const int cc = threadIdx.x & 15;   // 0..15 float4 column
    #pragma unroll
    for (int base = 0; base < 80; base += 16) {
        const int r = base + rr;
        if (r < 65) {
            const int x = x0 - 1 + r;
            float4 f = make_float4(0.0f, 0.0f, 0.0f, 0.0f);
            if (x >= 0)
                f = *(const float4*)&vol[(x << 16) | (y << 8) | (z0 + (cc << 2))];
            tile[r][(cc << 2) + 0] = f.x;
            tile[r][(cc << 2) + 1] = f.y;
            tile[r][(cc << 2) + 2] = f.z;
            tile[r][(cc << 2) + 3] = f.w;
        }
    }
    __syncthreads();

    const int lane = threadIdx.x & 63;
    const int row4 = threadIdx.x >> 6;  // 0..3
    for (int r = row4; r < 64; r += 4) {
        const int z = z0 + r;
        const unsigned base = (unsigned)((z << 8) | y) * PAIR_R;
        vhp[base + x0 + lane] =
            __halves2half2(__float2half(tile[lane][r]), __float2half(tile[lane + 1][r]));
    }
    if ((t4 & 3) == 3) {
        for (int r = row4; r < 64; r += 4) {
            const int z = z0 + r;
            const unsigned base = (unsigned)((z << 8) | y) * PAIR_R;
            if (lane == 0) {
                vhp[base + 256] = __halves2half2(__float2half(tile[64][r]), __float2half(0.0f));
                vhp[base + 257] = __halves2half2(__float2half(0.0f), __float2half(0.0f));
            }
        }
    }
}

// Per-dimension slab: tighten [tlo, thi] to where s + t*r is in [lo, hi].
__device__ __forceinline__ void slab(float s, float r, float lo, float hi,
                                     float& tlo, float& thi) {
    if (fabsf(r) > 1e-8f) {
        const float inv = 1.0f / r;
        const float ta  = (lo - s) * inv;
        const float tb  = (hi - s) * inv;
        tlo = fmaxf(tlo, fminf(ta, tb));
        thi = fminf(thi, fmaxf(ta, tb));
    } else if (s < lo || s > hi) {
        tlo = 2.0f; thi = -1.0f;  // empty
    }
}

struct RayCfg {
    float rx, ry, rz, length;
    int k_lo, k_hi;   // loose window (outside: exactly zero via masks)
    int s_lo, s_hi;   // strict window (inside: all masks 1, no clamps needed)
};

__device__ __forceinline__ void cfg_windows(float sx, float sy, float sz, RayCfg& c) {
    // loose: any coord outside [-1,256] contributes exactly 0
    float tlo = 0.0f, thi = 1.0f;
    slab(sx, c.rx, -1.02f, 256.02f, tlo, thi);
    slab(sy, c.ry, -1.02f, 256.02f, tlo, thi);
    slab(sz, c.rz, -1.02f, 256.02f, tlo, thi);
    c.k_lo = 0; c.k_hi = -1;
    if (thi >= tlo) {
        c.k_lo = max(0,   (int)ceilf(tlo * 255.0f - 1e-3f));
        c.k_hi = min(255, (int)floorf(thi * 255.0f + 1e-3f));
    }
    // strict: all coords in (0, 255) -> ix,iy,iz in [0,254], masks all 1
    float slo = 0.0f, shi = 1.0f;
    slab(sx, c.rx, 0.01f, 254.99f, slo, shi);
    slab(sy, c.ry, 0.01f, 254.99f, slo, shi);
    slab(sz, c.rz, 0.01f, 254.99f, slo, shi);
    c.s_lo = 1; c.s_hi = -1;
    if (shi >= slo) {
        c.s_lo = (int)ceilf(slo * 255.0f + 1e-3f);
        c.s_hi = (int)floorf(shi * 255.0f - 1e-3f);
    }
}

// Shared pose math; A = pixel (u, v0), B = pixel (u, v0+1).
__device__ __forceinline__ void ray_setup2(const float* __restrict__ batch,
                                           int b, int u, int v0,
                                           float& sx, float& sy, float& sz,
                                           RayCfg& A, RayCfg& B) {
    const float a  = batch[b * 6 + 0];
    const float be = batch[b * 6 + 1];
    const float g  = batch[b * 6 + 2];
    const float tx = batch[b * 6 + 3];
    const float ty = batch[b * 6 + 4];
    const float tz = batch[b * 6 + 5];

    float sa, ca, sb, cb, sg, cg;
    sincosf(a, &sa, &ca);
    sincosf(be, &sb, &cb);
    sincosf(g, &sg, &cg);

    const float R00 = ca * cb;
    const float R01 = ca * sb * sg - sa * cg;
    const float R02 = sa * sg + ca * sb * cg;
    const float R10 = sa * cb;
    const float R11 = ca * cg + sa * sb * sg;
    const float R12 = sa * sb * cg - ca * sg;
    const float R20 = -sb;
    const float R21 = cb * sg;
    const float R22 = cb * cg;

    sx = 128.0f + tx + kSAD * R02;
    sy = 128.0f + ty + kSAD * R12;
    sz = 128.0f + tz + kSAD * R22;

    const float uu = u * kPX - kPIERCE;
    const float vv = v0 * kPX - kPIERCE;
    A.rx = uu * R00 + vv * R01 - (kSAD + kDAD) * R02;
    A.ry = uu * R10 + vv * R11 - (kSAD + kDAD) * R12;
    A.rz = uu * R20 + vv * R21 - (kSAD + kDAD) * R22;
    B.rx = A.rx + kPX * R01;
    B.ry = A.ry + kPX * R11;
    B.rz = A.rz + kPX * R21;
    A.length = sqrtf(A.rx * A.rx + A.ry * A.ry + A.rz * A.rz);
    B.length = sqrtf(B.rx * B.rx + B.ry * B.ry + B.rz * B.rz);
    cfg_windows(sx, sy, sz, A);
    cfg_windows(sx, sy, sz, B);
}

// Interior sample: all 8 corners in-bounds, no masks/clamps. Bit-exact equal
// to the slow path when the strict window guarantee holds.
__device__ __forceinline__ float tri_fast(const __half2* __restrict__ vhp,
                                          float sx, float sy, float sz,
                                          const RayCfg& c, float t) {
    const float px = fmaf(t, c.rx, sx);
    const float py = fmaf(t, c.ry, sy);
    const float pz = fmaf(t, c.rz, sz);
    const float fx = floorf(px), fy = floorf(py), fz = floorf(pz);
    const int ix = (int)fx, iy = (int)fy, iz = (int)fz;
    const float wx = px - fx, wy = py - fy, wz = pz - fz;

    const unsigned base = (unsigned)iz * 66048u + (unsigned)iy * 258u + (unsigned)(ix + 1);
    const __half2 q00 = vhp[base];            // (v000, v100)  z0 y0
    const __half2 q01 = vhp[base + 66048u];   // z1 y0
    const __half2 q10 = vhp[base + 258u];     // z0 y1
    const __half2 q11 = vhp[base + 66306u];   // z1 y1

    const float wx0 = 1.0f - wx, wy0 = 1.0f - wy, wz0 = 1.0f - wz;
    const float a00 = __low2float(q00) * wx0 + __high2float(q00) * wx;
    const float a01 = __low2float(q01) * wx0 + __high2float(q01) * wx;
    const float a10 = __low2float(q10) * wx0 + __high2float(q10) * wx;
    const float a11 = __low2float(q11) * wx0 + __high2float(q11) * wx;
    return (a00 * wz0 + a01 * wz) * wy0 + (a10 * wz0 + a11 * wz) * wy;
}

// Boundary sample: masks folded into weights, clamped addresses (proven r9).
__device__ __forceinline__ float tri_slow(const __half2* __restrict__ vhp,
                                          float sx, float sy, float sz,
                                          const RayCfg& c, float t) {
    const float px = fmaf(t, c.rx, sx);
    const float py = fmaf(t, c.ry, sy);
    const float pz = fmaf(t, c.rz, sz);
    const float fx = floorf(px), fy = floorf(py), fz = floorf(pz);
    const int ix = (int)fx, iy = (int)fy, iz = (int)fz;
    const float wx = px - fx, wy = py - fy, wz = pz - fz;

    const float mx0 = ((unsigned)ix       < 256u) ? 1.0f : 0.0f;
    const float mx1 = ((unsigned)(ix + 1) < 256u) ? 1.0f : 0.0f;
    const float my0 = ((unsigned)iy       < 256u) ? 1.0f : 0.0f;
    const float my1 = ((unsigned)(iy + 1) < 256u) ? 1.0f : 0.0f;
    const float mz0 = ((unsigned)iz       < 256u) ? 1.0f : 0.0f;
    const float mz1 = ((unsigned)(iz + 1) < 256u) ? 1.0f : 0.0f;

    const int i  = min(max(ix + 1, 0), 257);
    const int y0 = min(max(iy,     0), 255);
    const int y1 = min(max(iy + 1, 0), 255);
    const int z0 = min(max(iz,     0), 255);
    const int z1 = min(max(iz + 1, 0), 255);

    const unsigned zt0 = (unsigned)z0 * 66048u;
    const unsigned zt1 = (unsigned)z1 * 66048u;
    const unsigned yt0 = (unsigned)y0 * 258u;
    const unsigned yt1 = (unsigned)y1 * 258u;

    const __half2 q00 = vhp[zt0 + yt0 + i];
    const __half2 q01 = vhp[zt1 + yt0 + i];
    const __half2 q10 = vhp[zt0 + yt1 + i];
    const __half2 q11 = vhp[zt1 + yt1 + i];

    const float wx0 = (1.0f - wx) * mx0, wx1 = wx * mx1;
    const float wy0 = (1.0f - wy) * my0, wy1 = wy * my1;
    const float wz0 = (1.0f - wz) * mz0, wz1 = wz * mz1;

    const float a00 = __low2float(q00) * wx0 + __high2float(q00) * wx1;
    const float a01 = __low2float(q01) * wx0 + __high2float(q01) * wx1;
    const float a10 = __low2float(q10) * wx0 + __high2float(q10) * wx1;
    const float a11 = __low2float(q11) * wx0 + __high2float(q11) * wx1;
    return (a00 * wz0 + a01 * wz1) * wy0 + (a10 * wz0 + a11 * wz1) * wy1;
}

// Block = 512 threads = 8 waves; tile = 16u x 8v = 128 px; each lane owns the
// v-pair (u, v0) and (u, v0+1). Wave `seg` covers k = klo+seg, stride 8.
// Grid = 2 images * 512 tiles = 1024 blocks -> 8192 waves = 32/CU.
__global__ __launch_bounds__(512, 4) void drr_main_pk2(const __half2* __restrict__ vhp,
                                                       const float* __restrict__ batch,
                                                       float* __restrict__ raw,
                                                       unsigned* __restrict__ mm) {
    const int tid  = threadIdx.x;
    const int lane = tid & 63;
    const int seg  = tid >> 6;   // 0..7

    // XCD swizzle (bijective for 1024 = 8 x 128)
    const int blk = ((blockIdx.x & 7) << 7) | (blockIdx.x >> 3);
    const int b   = blk >> 9;            // 512 tiles per image
    const int ti  = blk & 511;
    const int u   = ((ti & 15) << 4) + (lane & 15);
    const int v0  = ((ti >> 4) << 3) + ((lane >> 4) << 1);

    float sx, sy, sz;
    RayCfg A, B;
    ray_setup2(batch, b, u, v0, sx, sy, sz, A, B);

    const int klo = min(A.k_lo, B.k_lo);
    const int khi = max(A.k_hi, B.k_hi);
    const int slo = max(A.s_lo, B.s_lo);
    const int shi = min(A.s_hi, B.s_hi);

    const float tstep = 1.0f / 255.0f;
    float sA = 0.0f, sB = 0.0f;
    for (int k = klo + seg; k <= khi; k += 8) {
        const float t = (float)k * tstep;
        if (k >= slo && k <= shi) {          // interior (wave-coherent mostly)
            sA += tri_fast(vhp, sx, sy, sz, A, t);
            sB += tri_fast(vhp, sx, sy, sz, B, t);
        } else {
            sA += tri_slow(vhp, sx, sy, sz, A, t);
            sB += tri_slow(vhp, sx, sy, sz, B, t);
        }
    }

    __shared__ float pA[8][64], pB[8][64];
    pA[seg][lane] = sA;
    pB[seg][lane] = sB;
    __syncthreads();

    if (tid < 64) {
        float tA = 0.0f, tB = 0.0f;
        #pragma unroll
        for (int s = 0; s < 8; ++s) { tA += pA[s][lane]; tB += pB[s][lane]; }
        const float rA = tA * (A.length * (1.0f / 256.0f));
        const float rB = tB * (B.length * (1.0f / 256.0f));
        raw[(b << 16) + (v0 << 8) + u]       = rA;
        raw[(b << 16) + ((v0 + 1) << 8) + u] = rB;

        float mn = fminf(rA, rB), mx = fmaxf(rA, rB);
        #pragma unroll
        for (int off = 32; off >= 1; off >>= 1) {
            mn = fminf(mn, __shfl_xor(mn, off));
            mx = fmaxf(mx, __shfl_xor(mx, off));
        }
        if (lane == 0) {
            atomicMin(&mm[2 * b + 0], __float_as_uint(mn));
            atomicMax(&mm[2 * b + 1], __float_as_uint(mx));
        }
    }
}

// ---------------- fallback (ws too small for pair array): f32 path ---------
__global__ __launch_bounds__(256) void drr_transpose(const float* __restrict__ vol,
                                                     float* __restrict__ volt) {
    __shared__ float tile[64][65];
    const int bid  = blockIdx.x;
    const int y    = bid >> 4;
    const int t4   = bid & 15;
    const int x0   = (t4 & 3) << 6;
    const int z0   = (t4 >> 2) << 6;
    const int lane = threadIdx.x & 63;
    const int row4 = threadIdx.x >> 6;

    #pragma unroll
    for (int i = 0; i < 16; ++i) {
        const int xr = (i << 2) + row4;
        tile[xr][lane] = vol[((x0 + xr) << 16) | (y << 8) | (z0 + lane)];
    }
    __syncthreads();
    #pragma unroll
    for (int i = 0; i < 16; ++i) {
        const int zr = (i << 2) + row4;
        volt[((z0 + zr) << 16) | (y << 8) | (x0 + lane)] = tile[lane][zr];
    }
}

__device__ __forceinline__ float tri_sample_f32(const float* __restrict__ vol,
                                                float sx, float sy, float sz,
                                                const RayCfg& c, float t) {
    const float px = fmaf(t, c.rx, sx);
    const float py = fmaf(t, c.ry, sy);
    const float pz = fmaf(t, c.rz, sz);
    const float fx = floorf(px), fy = floorf(py), fz = floorf(pz);
    const int ix = (int)fx, iy = (int)fy, iz = (int)fz;
    const float wx = px - fx, wy = py - fy, wz = pz - fz;
    const float mx0 = ((unsigned)ix       < 256u) ? 1.0f : 0.0f;
    const float mx1 = ((unsigned)(ix + 1) < 256u) ? 1.0f : 0.0f;
    const float my0 = ((unsigned)iy       < 256u) ? 1.0f : 0.0f;
    const float my1 = ((unsigned)(iy + 1) < 256u) ? 1.0f : 0.0f;
    const float mz0 = ((unsigned)iz       < 256u) ? 1.0f : 0.0f;
    const float mz1 = ((unsigned)(iz + 1) < 256u) ? 1.0f : 0.0f;
    const unsigned X0 = (unsigned)ix & 255u, X1 = (unsigned)(ix + 1) & 255u;
    const unsigned Y0 = ((unsigned)iy & 255u) << 8, Y1 = ((unsigned)(iy + 1) & 255u) << 8;
    const unsigned Z0 = ((unsigned)iz & 255u) << 16, Z1 = ((unsigned)(iz + 1) & 255u) << 16;
    const float v000 = vol[Z0 | Y0 | X0];
    const float v001 = vol[Z1 | Y0 | X0];
    const float v010 = vol[Z0 | Y1 | X0];
    const float v011 = vol[Z1 | Y1 | X0];
    const float v100 = vol[Z0 | Y0 | X1];
    const float v101 = vol[Z1 | Y0 | X1];
    const float v110 = vol[Z0 | Y1 | X1];
    const float v111 = vol[Z1 | Y1 | X1];
    const float wx0 = (1.0f - wx) * mx0, wx1 = wx * mx1;
    const float wy0 = (1.0f - wy) * my0, wy1 = wy * my1;
    const float wz0 = (1.0f - wz) * mz0, wz1 = wz * mz1;
    const float c00 = v000 * wz0 + v001 * wz1;
    const float c01 = v010 * wz0 + v011 * wz1;
    const float c10 = v100 * wz0 + v101 * wz1;
    const float c11 = v110 * wz0 + v111 * wz1;
    return (c00 * wy0 + c01 * wy1) * wx0 + (c10 * wy0 + c11 * wy1) * wx1;
}

__global__ __launch_bounds__(256, 4) void drr_main_f32(const float* __restrict__ volt,
                                                       const float* __restrict__ batch,
                                                       float* __restrict__ raw,
                                                       unsigned* __restrict__ mm) {
    const int tid  = threadIdx.x;
    const int lane = tid & 63;
    const int seg  = tid >> 6;
    const int tile = blockIdx.x;
    const int b    = tile >> 10;
    const int ti   = tile & 1023;
    const int u    = ((ti & 15) << 4) + (lane & 15);
    const int v    = ((ti >> 4) << 2) + (lane >> 4);

    float sx, sy, sz;
    RayCfg A, B;
    ray_setup2(batch, b, u, v, sx, sy, sz, A, B);  // use A only

    const float tstep = 1.0f / 255.0f;
    float sum = 0.0f;
    for (int k = A.k_lo + seg; k <= A.k_hi; k += 4)
        sum += tri_sample_f32(volt, sx, sy, sz, A, (float)k * tstep);

    __shared__ float part[4][64];
    part[seg][lane] = sum;
    __syncthreads();

    if (tid < 64) {
        const float s = part[0][lane] + part[1][lane] + part[2][lane] + part[3][lane];
        const float rawv = s * (A.length * (1.0f / 256.0f));
        raw[(b << 16) + (v << 8) + u] = rawv;
        float mn = rawv, mx = rawv;
        #pragma unroll
        for (int off = 32; off >= 1; off >>= 1) {
            mn = fminf(mn, __shfl_xor(mn, off));
            mx = fmaxf(mx, __shfl_xor(mx, off));
        }
        if (lane == 0) {
            atomicMin(&mm[2 * b + 0], __float_as_uint(mn));
            atomicMax(&mm[2 * b + 1], __float_as_uint(mx));
        }
    }
}

__global__ __launch_bounds__(256) void drr_norm(float* __restrict__ img,
                                                const unsigned* __restrict__ mm) {
    const int gid = blockIdx.x * 256 + threadIdx.x;
    const int b   = gid >> 16;
    const float mn  = __uint_as_float(mm[2 * b + 0]);
    const float mx  = __uint_as_float(mm[2 * b + 1]);
    const float inv = 1.0f / (mx - mn);
    img[gid] = 1.0f - (img[gid] - mn) * inv;
}

extern "C" void kernel_launch(void* const* d_in, const int* in_sizes, int n_in,
                              void* d_out, int out_size, void* d_ws, size_t ws_size,
                              hipStream_t stream) {
    const float* vol   = (const float*)d_in[0];
    const float* batch = (const float*)d_in[1];
    float* out         = (float*)d_out;

    if (ws_size >= (size_t)PAIR_BYTES + 16) {
        __half2*  vhp = (__half2*)d_ws;
        unsigned* mm  = (unsigned*)((char*)d_ws + PAIR_BYTES);
        drr_pack<<<4096, 256, 0, stream>>>(vol, vhp, mm);
        drr_main_pk2<<<1024, 512, 0, stream>>>(vhp, batch, out, mm);
        drr_norm<<<512, 256, 0, stream>>>(out, mm);
    } else {
        float*    volt = (float*)d_ws;
        unsigned* mm   = (unsigned*)((char*)d_ws + VOL_BYTES);
        drr_init_mm<<<1, 64, 0, stream>>>(mm);
        drr_transpose<<<4096, 256, 0, stream>>>(vol, volt);
        drr_main_f32<<<2048, 256, 0, stream>>>(volt, batch, out, mm);
        drr_norm<<<512, 256, 0, stream>>>(out, mm);
    }
}